// Round 9
// baseline (451.330 us; speedup 1.0000x reference)
//
#include <hip/hip_runtime.h>
#include <math.h>

// MinkowskiInstanceNorm: segment instance-norm, N x C=32, S<=64 segments (sorted seg_ids).
// ws (floats):
//   SHARDS @0: 64 shards x 4160 floats  (sum[2048], sq[2048], cnt[64])  = 266240
//   SCALE @266240 (2048), SHIFT @268288 (2048)

#define SHARD_F  4160
#define WS_SCALE 266240
#define WS_SHIFT 268288

typedef float f32x4 __attribute__((ext_vector_type(4)));

__global__ __launch_bounds__(256) void zero_ws_kernel(float* __restrict__ ws) {
    int t = blockIdx.x * blockDim.x + threadIdx.x;
    if (t < 64 * SHARD_F) ws[t] = 0.0f;
}

#define FLUSH()                                                      \
    do {                                                             \
        int bse = cur * 32 + cg * 4;                                 \
        atomicAdd(&s_sum[bse + 0], acc.x);                           \
        atomicAdd(&s_sum[bse + 1], acc.y);                           \
        atomicAdd(&s_sum[bse + 2], acc.z);                           \
        atomicAdd(&s_sum[bse + 3], acc.w);                           \
        atomicAdd(&s_sq[bse + 0], accq.x);                           \
        atomicAdd(&s_sq[bse + 1], accq.y);                           \
        atomicAdd(&s_sq[bse + 2], accq.z);                           \
        atomicAdd(&s_sq[bse + 3], accq.w);                           \
        if (cg == 0 && rcnt != 0.0f) atomicAdd(&s_cnt[cur], rcnt);   \
    } while (0)

// EXACT apply-shaped sweep: 4096 blocks x 256 threads, grid-stride, NT loads.
// Per-thread register run-binning (seg non-decreasing along i) -> LDS bins ->
// sharded global partials (shard = blockIdx & 63).
__global__ __launch_bounds__(256) void reduce_kernel(
        const f32x4* __restrict__ f4, const int* __restrict__ seg,
        float* __restrict__ ws, int total4) {
    __shared__ float s_sum[2048];
    __shared__ float s_sq[2048];
    __shared__ float s_cnt[64];
    int t = threadIdx.x;
    for (int j = t; j < 2048; j += 256) { s_sum[j] = 0.0f; s_sq[j] = 0.0f; }
    if (t < 64) s_cnt[t] = 0.0f;
    __syncthreads();

    int cg  = t & 7;
    int gsz = gridDim.x * blockDim.x;
    f32x4 acc  = {0.f, 0.f, 0.f, 0.f};
    f32x4 accq = {0.f, 0.f, 0.f, 0.f};
    float rcnt = 0.0f;
    int cur = -1;

    for (int i = blockIdx.x * blockDim.x + t; i < total4; i += gsz) {
        int s = seg[i >> 3];
        f32x4 v = __builtin_nontemporal_load(&f4[i]);
        if (s != cur) {
            if (cur >= 0) FLUSH();
            cur = s;
            acc  = (f32x4){0.f, 0.f, 0.f, 0.f};
            accq = (f32x4){0.f, 0.f, 0.f, 0.f};
            rcnt = 0.0f;
        }
        acc  += v;
        accq += v * v;
        rcnt += (cg == 0) ? 1.0f : 0.0f;
    }
    if (cur >= 0) FLUSH();
    __syncthreads();

    // LDS bins -> this block's shard (64-deep contention, temporally spread)
    float* shard = ws + (blockIdx.x & 63) * SHARD_F;
    for (int j = t; j < 2048; j += 256) {
        float v1 = s_sum[j];
        float v2 = s_sq[j];
        if (v1 != 0.0f) atomicAdd(&shard[j], v1);
        if (v2 != 0.0f) atomicAdd(&shard[2048 + j], v2);
    }
    if (t < 64) {
        float c = s_cnt[t];
        if (c != 0.0f) atomicAdd(&shard[4096 + t], c);
    }
}

// 1 block x 256 threads: sum 64 shards (1 MB, L2-resident), write scale/shift.
__global__ void stats_kernel(const float* __restrict__ w,
                             const float* __restrict__ b,
                             const int* __restrict__ nsp,
                             float* __restrict__ ws) {
    int t  = threadIdx.x;
    int ns = min(*nsp, 64);
    for (int o = t; o < ns * 32; o += 256) {
        int s = o >> 5, c = o & 31;
        float S = 0.f, Q = 0.f, C = 0.f;
        for (int sh = 0; sh < 64; ++sh) {
            const float* base = ws + sh * SHARD_F;
            S += base[o];
            Q += base[2048 + o];
            C += base[4096 + s];
        }
        float cnt  = fmaxf(C, 1.0f);
        float mean = S / cnt;
        float var  = fmaxf(Q / cnt - mean * mean, 0.0f);
        float inv  = rsqrtf(var + 1e-8f);
        float sc   = inv * w[c];
        ws[WS_SCALE + o] = sc;
        ws[WS_SHIFT + o] = b[c] - mean * sc;
    }
}

__global__ __launch_bounds__(256) void apply_kernel(
        const float* __restrict__ feats, const int* __restrict__ seg,
        const float* __restrict__ ws, float* __restrict__ out, int total4) {
    const f32x4* f4 = (const f32x4*)feats;
    f32x4*       o4 = (f32x4*)out;
    const f32x4* scale4 = (const f32x4*)(ws + WS_SCALE);
    const f32x4* shift4 = (const f32x4*)(ws + WS_SHIFT);
    int stride = gridDim.x * blockDim.x;
    for (int i = blockIdx.x * blockDim.x + threadIdx.x; i < total4; i += stride) {
        int row = i >> 3, cg = i & 7;
        int s = seg[row];
        f32x4 v  = __builtin_nontemporal_load(&f4[i]);
        f32x4 sc = scale4[s * 8 + cg];
        f32x4 sh = shift4[s * 8 + cg];
        f32x4 o;
        o.x = fmaf(v.x, sc.x, sh.x); o.y = fmaf(v.y, sc.y, sh.y);
        o.z = fmaf(v.z, sc.z, sh.z); o.w = fmaf(v.w, sc.w, sh.w);
        __builtin_nontemporal_store(o, &o4[i]);
    }
}

extern "C" void kernel_launch(void* const* d_in, const int* in_sizes, int n_in,
                              void* d_out, int out_size, void* d_ws, size_t ws_size,
                              hipStream_t stream) {
    const float* feats = (const float*)d_in[0];
    const int*   seg   = (const int*)d_in[1];
    const float* w     = (const float*)d_in[2];
    const float* b     = (const float*)d_in[3];
    const int*   nsp   = (const int*)d_in[4];
    float* out = (float*)d_out;
    float* ws  = (float*)d_ws;

    int N = in_sizes[1];
    int total4 = N * 8;

    hipLaunchKernelGGL(zero_ws_kernel, dim3((64 * SHARD_F + 255) / 256), dim3(256),
                       0, stream, ws);
    hipLaunchKernelGGL(reduce_kernel, dim3(4096), dim3(256), 0, stream,
                       (const f32x4*)feats, seg, ws, total4);
    hipLaunchKernelGGL(stats_kernel, dim3(1), dim3(256), 0, stream,
                       w, b, nsp, ws);
    hipLaunchKernelGGL(apply_kernel, dim3(4096), dim3(256), 0, stream,
                       feats, seg, ws, out, total4);
}

// Round 10
// 142.291 us; speedup vs baseline: 3.1719x; 3.1719x over previous
//
#include <hip/hip_runtime.h>
#include <math.h>

// MinkowskiInstanceNorm: segment instance-norm, N x C=32, S<=64 segments (sorted seg_ids).
// ws (floats): SHARDS @0: 8 x 4160 (sum[2048], sq[2048], cnt[64]) = 33280
//              SCALE @33280 (2048), SHIFT @35328 (2048)

#define NSH      8
#define SHARD_F  4160
#define WS_SCALE (NSH * SHARD_F)
#define WS_SHIFT (WS_SCALE + 2048)

#define NB    4      // DMA pipeline depth per wave (1KB slots)
#define STEPS 32     // 32 x 1KB = 32KB per wave = 2048 float4 = 256 rows

typedef float f32x4 __attribute__((ext_vector_type(4)));

typedef const __attribute__((address_space(1))) unsigned int ga_u32;
typedef __attribute__((address_space(3))) unsigned int la_u32;
#define GLL16(gp, lp) \
    __builtin_amdgcn_global_load_lds((ga_u32*)(gp), (la_u32*)(lp), 16, 0, 0)

__global__ __launch_bounds__(256) void zero_ws_kernel(float* __restrict__ ws) {
    int t = blockIdx.x * blockDim.x + threadIdx.x;
    if (t < NSH * SHARD_F) ws[t] = 0.0f;
}

// Per-wave async-DMA reduce. Wave g = blockIdx*4+wid owns float4 [g*2048, (g+1)*2048).
__global__ __launch_bounds__(256) void reduce_kernel(
        const float* __restrict__ feats, const int* __restrict__ seg,
        float* __restrict__ ws, int total4, int N) {
    __shared__ __align__(16) char dma[4 * NB * 1024];   // 16 KB: 4 waves x 4 slots x 1KB
    __shared__ float s_sum[2048];
    __shared__ float s_sq[2048];
    __shared__ float s_cnt[64];
    int t = threadIdx.x;
    for (int j = t; j < 2048; j += 256) { s_sum[j] = 0.0f; s_sq[j] = 0.0f; }
    if (t < 64) s_cnt[t] = 0.0f;
    __syncthreads();

    int wid  = t >> 6;
    int lane = t & 63;
    int cg   = lane & 7;
    const f32x4* f4 = (const f32x4*)feats;
    long ebase = ((long)blockIdx.x * 4 + wid) * 2048;

    if (ebase < total4) {
        long eend = ebase + 2048;
        if (eend > total4) eend = total4;
        int row0 = (int)(ebase >> 3);
        int row1 = (int)((eend - 1) >> 3);
        int sA = seg[row0];
        int sB = seg[row1];
        f32x4 acc  = {0.f, 0.f, 0.f, 0.f};
        f32x4 accq = {0.f, 0.f, 0.f, 0.f};

        if (sA == sB && (eend - ebase) == 2048) {
            // ---- fast path: counted-vmcnt DMA pipeline, wave-private slots ----
            const char* g = (const char*)(f4 + ebase) + lane * 16;
            char* lb = &dma[wid * (NB * 1024)];
            asm volatile("s_waitcnt vmcnt(0)" ::: "memory");   // exact counting
            #pragma unroll
            for (int k = 0; k < NB; ++k)
                GLL16(g + k * 1024, lb + k * 1024);
            for (int k = 0; k < STEPS - NB; ++k) {
                asm volatile("s_waitcnt vmcnt(3)" ::: "memory");   // oldest landed
                __builtin_amdgcn_sched_barrier(0);
                f32x4 v = *(const f32x4*)(lb + (k & (NB - 1)) * 1024 + lane * 16);
                acc  += v;
                accq += v * v;
                __builtin_amdgcn_sched_barrier(0);
                GLL16(g + (k + NB) * 1024, lb + (k & (NB - 1)) * 1024);
            }
            asm volatile("s_waitcnt vmcnt(0)" ::: "memory");
            __builtin_amdgcn_sched_barrier(0);
            #pragma unroll
            for (int k = STEPS - NB; k < STEPS; ++k) {
                f32x4 v = *(const f32x4*)(lb + (k & (NB - 1)) * 1024 + lane * 16);
                acc  += v;
                accq += v * v;
            }
            // combine lanes sharing channel-group (lane, lane^8, lane^16, lane^32)
            #pragma unroll
            for (int m = 8; m <= 32; m <<= 1) {
                acc.x  += __shfl_xor(acc.x, m);  acc.y  += __shfl_xor(acc.y, m);
                acc.z  += __shfl_xor(acc.z, m);  acc.w  += __shfl_xor(acc.w, m);
                accq.x += __shfl_xor(accq.x, m); accq.y += __shfl_xor(accq.y, m);
                accq.z += __shfl_xor(accq.z, m); accq.w += __shfl_xor(accq.w, m);
            }
            if (lane < 8) {
                int bse = sA * 32 + lane * 4;
                atomicAdd(&s_sum[bse + 0], acc.x);
                atomicAdd(&s_sum[bse + 1], acc.y);
                atomicAdd(&s_sum[bse + 2], acc.z);
                atomicAdd(&s_sum[bse + 3], acc.w);
                atomicAdd(&s_sq[bse + 0], accq.x);
                atomicAdd(&s_sq[bse + 1], accq.y);
                atomicAdd(&s_sq[bse + 2], accq.z);
                atomicAdd(&s_sq[bse + 3], accq.w);
            }
            if (lane == 0) atomicAdd(&s_cnt[sA], 256.0f);
        } else {
            // ---- slow path (boundary/partial waves, <=4 in grid) ----
            for (long e = ebase + lane; e < eend; e += 64) {
                int s = seg[(int)(e >> 3)];
                f32x4 v = f4[e];
                int bse = s * 32 + cg * 4;
                atomicAdd(&s_sum[bse + 0], v.x);
                atomicAdd(&s_sum[bse + 1], v.y);
                atomicAdd(&s_sum[bse + 2], v.z);
                atomicAdd(&s_sum[bse + 3], v.w);
                atomicAdd(&s_sq[bse + 0], v.x * v.x);
                atomicAdd(&s_sq[bse + 1], v.y * v.y);
                atomicAdd(&s_sq[bse + 2], v.z * v.z);
                atomicAdd(&s_sq[bse + 3], v.w * v.w);
                if (cg == 0) atomicAdd(&s_cnt[s], 1.0f);
            }
        }
    }
    __syncthreads();

    // LDS bins -> this block's shard
    float* shard = ws + (blockIdx.x & (NSH - 1)) * SHARD_F;
    for (int j = t; j < 2048; j += 256) {
        float a = s_sum[j];
        float q = s_sq[j];
        if (a != 0.0f) atomicAdd(&shard[j], a);
        if (q != 0.0f) atomicAdd(&shard[2048 + j], q);
    }
    if (t < 64) {
        float c = s_cnt[t];
        if (c != 0.0f) atomicAdd(&shard[4096 + t], c);
    }
}

__global__ void stats_kernel(const float* __restrict__ w,
                             const float* __restrict__ b,
                             const int* __restrict__ nsp,
                             float* __restrict__ ws) {
    int t  = threadIdx.x;
    int ns = min(*nsp, 64);
    for (int o = t; o < ns * 32; o += 256) {
        int s = o >> 5, c = o & 31;
        float S = 0.f, Q = 0.f, C = 0.f;
        #pragma unroll
        for (int sh = 0; sh < NSH; ++sh) {
            const float* base = ws + sh * SHARD_F;
            S += base[o];
            Q += base[2048 + o];
            C += base[4096 + s];
        }
        float cnt  = fmaxf(C, 1.0f);
        float mean = S / cnt;
        float var  = fmaxf(Q / cnt - mean * mean, 0.0f);
        float inv  = rsqrtf(var + 1e-8f);
        float sc   = inv * w[c];
        ws[WS_SCALE + o] = sc;
        ws[WS_SHIFT + o] = b[c] - mean * sc;
    }
}

__global__ __launch_bounds__(256) void apply_kernel(
        const float* __restrict__ feats, const int* __restrict__ seg,
        const float* __restrict__ ws, float* __restrict__ out, int total4) {
    const f32x4* f4 = (const f32x4*)feats;
    f32x4*       o4 = (f32x4*)out;
    const f32x4* scale4 = (const f32x4*)(ws + WS_SCALE);
    const f32x4* shift4 = (const f32x4*)(ws + WS_SHIFT);
    int stride = gridDim.x * blockDim.x;
    for (int i = blockIdx.x * blockDim.x + threadIdx.x; i < total4; i += stride) {
        int row = i >> 3, cg = i & 7;
        int s = seg[row];
        f32x4 v  = f4[i];                       // plain load: keep feats L3-hot
        f32x4 sc = scale4[s * 8 + cg];
        f32x4 sh = shift4[s * 8 + cg];
        f32x4 o;
        o.x = fmaf(v.x, sc.x, sh.x); o.y = fmaf(v.y, sc.y, sh.y);
        o.z = fmaf(v.z, sc.z, sh.z); o.w = fmaf(v.w, sc.w, sh.w);
        __builtin_nontemporal_store(o, &o4[i]); // out shouldn't evict feats
    }
}

extern "C" void kernel_launch(void* const* d_in, const int* in_sizes, int n_in,
                              void* d_out, int out_size, void* d_ws, size_t ws_size,
                              hipStream_t stream) {
    const float* feats = (const float*)d_in[0];
    const int*   seg   = (const int*)d_in[1];
    const float* w     = (const float*)d_in[2];
    const float* b     = (const float*)d_in[3];
    const int*   nsp   = (const int*)d_in[4];
    float* out = (float*)d_out;
    float* ws  = (float*)d_ws;

    int N = in_sizes[1];
    int total4 = N * 8;
    int nwaves = (total4 + 2047) / 2048;
    int nblk_r = (nwaves + 3) / 4;

    hipLaunchKernelGGL(zero_ws_kernel, dim3((NSH * SHARD_F + 255) / 256), dim3(256),
                       0, stream, ws);
    hipLaunchKernelGGL(reduce_kernel, dim3(nblk_r), dim3(256), 0, stream,
                       feats, seg, ws, total4, N);
    hipLaunchKernelGGL(stats_kernel, dim3(1), dim3(256), 0, stream,
                       w, b, nsp, ws);
    hipLaunchKernelGGL(apply_kernel, dim3(4096), dim3(256), 0, stream,
                       feats, seg, ws, out, total4);
}